// Round 23
// baseline (96.161 us; speedup 1.0000x reference)
//
#include <hip/hip_runtime.h>
#include <hip/hip_bf16.h>
#include <stdint.h>

// Problem constants (from reference setup_inputs)
#define MB 256
#define LW 200      // words per batch
#define NS 5        // senses per word
#define DD 128      // embedding dim
#define OO 50000    // output vocab
#define LSTOK 1000  // LW*NS

#define NSTRIPES 782   // ceil(50000/64)
#define EMB_BLK 391    // ceil(50000*128 / 16384)

typedef __attribute__((ext_vector_type(8))) short bf16x8;
typedef __attribute__((ext_vector_type(4))) float f32x4;

__device__ inline unsigned short f2bf(float f){
  unsigned u = __float_as_uint(f);
  unsigned r = (u + 0x7fffu + ((u >> 16) & 1u)) >> 16;  // RNE
  return (unsigned short)r;
}
__device__ inline unsigned packbf(float a, float b){
  return (unsigned)f2bf(a) | ((unsigned)f2bf(b) << 16);
}
__device__ inline float lo16f(unsigned p){ return __uint_as_float(p << 16); }
__device__ inline float hi16f(unsigned p){ return __uint_as_float(p & 0xffff0000u); }
__device__ inline float wsum64(float v){
  #pragma unroll
  for (int o = 1; o < 64; o <<= 1) v += __shfl_xor(v, o, 64);
  return v;
}
__device__ inline float wmax64(float v){
  #pragma unroll
  for (int o = 1; o < 64; o <<= 1) v = fmaxf(v, __shfl_xor(v, o, 64));
  return v;
}
// dot of 8 bf16 (packed in uint4) with 8 f32 (two float4)
__device__ inline float dot8(uint4 r, float4 a, float4 b){
  return lo16f(r.x)*a.x + hi16f(r.x)*a.y + lo16f(r.y)*a.z + hi16f(r.y)*a.w
       + lo16f(r.z)*b.x + hi16f(r.z)*b.y + lo16f(r.w)*b.z + hi16f(r.w)*b.w;
}
// unweighted accumulate of 8 bf16 into two float4
__device__ inline void acc8(uint4 r, float4& x, float4& y){
  x.x += lo16f(r.x); x.y += hi16f(r.x); x.z += lo16f(r.y); x.w += hi16f(r.y);
  y.x += lo16f(r.z); y.y += hi16f(r.z); y.z += lo16f(r.w); y.w += hi16f(r.w);
}
// weighted accumulate
__device__ inline void wacc8(uint4 r, float w, float4& x, float4& y){
  x.x += w*lo16f(r.x); x.y += w*hi16f(r.x); x.z += w*lo16f(r.y); x.w += w*hi16f(r.y);
  y.x += w*lo16f(r.z); y.y += w*hi16f(r.z); y.z += w*lo16f(r.w); y.w += w*hi16f(r.w);
}
// butterfly sum within 16-lane groups
__device__ inline float gsum16(float v){
  v += __shfl_xor(v, 1, 64);
  v += __shfl_xor(v, 2, 64);
  v += __shfl_xor(v, 4, 64);
  v += __shfl_xor(v, 8, 64);
  return v;
}
// cross-group (within-wave) sum
__device__ inline float xg(float v){
  v += __shfl_xor(v, 16, 64);
  v += __shfl_xor(v, 32, 64);
  return v;
}
// Per-wave int64-vs-int32 sniff: high dwords of first 64 elements all zero -> int64.
__device__ inline int sniff_f(const unsigned* p, int l){
  unsigned v = p[2*l + 1];
  return (__ballot(v != 0u) == 0ull) ? 1 : 0;
}

// ---------------------------------------------------------------------------
// k_prep (proven): blocks [0,NSTRIPES): W -> Wt (bf16, transposed)
//                  blocks [NSTRIPES, +EMB_BLK): emb f32 -> embB bf16
__global__ __launch_bounds__(256) void k_prep(const float* __restrict__ W,
                                              const float* __restrict__ emb,
                                              unsigned short* __restrict__ Wt,
                                              unsigned* __restrict__ embB){
  int blk = blockIdx.x, t = threadIdx.x;
  if (blk < NSTRIPES){
    __shared__ float tile[64][129];
    long long n0 = (long long)blk * 64;
    int j = t & 63, kk = t >> 6;
    #pragma unroll
    for (int k = kk; k < 128; k += 4){
      float v = 0.f;
      if (n0 + j < OO) v = W[(long long)k*OO + n0 + j];
      tile[j][k] = v;
    }
    __syncthreads();
    #pragma unroll
    for (int c = t; c < 4096; c += 256){
      int row = c >> 6, dw = c & 63;
      if (n0 + row < OO){
        unsigned pr = packbf(tile[row][2*dw], tile[row][2*dw+1]);
        ((unsigned*)Wt)[(n0 + row)*64 + dw] = pr;
      }
    }
  } else {
    long long base = (long long)(blk - NSTRIPES) * 16384;
    for (int i = t; i < 4096; i += 256){
      long long idx = base + (long long)i*4;
      if (idx < (long long)OO*DD){
        float4 v = *(const float4*)(emb + idx);
        uint2 o; o.x = packbf(v.x, v.y); o.y = packbf(v.z, v.w);
        *(uint2*)(embB + (idx >> 1)) = o;
      }
    }
  }
}

// ---------------------------------------------------------------------------
// Fused attention v9: 512 threads (8 waves, 32 groups of 16 lanes), 1 block
// per batch. Same algorithm as r12's proven body, but at 512 threads the
// LDS-capped occupancy (1 block/CU) relaxes the VGPR budget (r5 evidence:
// 88 VGPR granted), enabling 2-word ILP in sweeps 2/3: 10 rows (40 VGPR)
// in flight -> 2x outstanding gather bytes per CU.
__global__ __launch_bounds__(512)
void k_attn(
    const int* __restrict__ in32, const float* __restrict__ lwp,
    const unsigned char* __restrict__ maskp, const unsigned* __restrict__ embB,
    const float* __restrict__ w_attn, const float* __restrict__ b_attn_p,
    unsigned short* __restrict__ hB)
{
  __shared__ float wm[LW*DD];    // word_mean f32: 100 KB
  __shared__ float red[8*DD];    // 4 KB (8 wave rows)
  __shared__ int   idL[1024];
  __shared__ float gm[DD];
  __shared__ float cx[DD];
  __shared__ float waL[DD];
  __shared__ float wimp[LW];
  __shared__ float ww[LW];

  int b = blockIdx.x, t = threadIdx.x;
  int wv = t >> 6, l = t & 63;   // 8 waves
  int g = l >> 4, q16 = l & 15;
  int G = wv*4 + g;              // group id 0..31
  int f = sniff_f((const unsigned*)in32, l);
  long long base = (long long)b * LSTOK;
  float lw = lwp[b];

  idL[t] = (t < LSTOK) ? in32[(base + t) << f] : 0;
  {
    int t2 = t + 512;
    idL[t2] = (t2 < LSTOK) ? in32[(base + t2) << f] : 0;
  }
  if (t < DD) waL[t] = w_attn[t];
  __syncthreads();

  // ---- Sweep 1: gmean (32 tokens per group)
  {
    float4 s0v = {0,0,0,0}, s1v = {0,0,0,0};
    #pragma unroll 4
    for (int j = 0; j < 32; j++){
      int id = idL[G*32 + j];
      uint4 r = *(const uint4*)(embB + (long long)id*64 + (q16 << 2));
      acc8(r, s0v, s1v);
    }
    s0v.x = xg(s0v.x); s0v.y = xg(s0v.y); s0v.z = xg(s0v.z); s0v.w = xg(s0v.w);
    s1v.x = xg(s1v.x); s1v.y = xg(s1v.y); s1v.z = xg(s1v.z); s1v.w = xg(s1v.w);
    if (g == 0){
      *(float4*)&red[wv*DD + q16*8]     = s0v;
      *(float4*)&red[wv*DD + q16*8 + 4] = s1v;
    }
  }
  __syncthreads();
  if (t < DD){
    float s = 0.f;
    #pragma unroll
    for (int r = 0; r < 8; r++) s += red[r*DD + t];
    gm[t] = s * lw * 0.2f;
  }
  __syncthreads();

  // ---- Sweep 2: words G+32k (k=0..5) + tail; 2-word ILP
  {
    float4 g0v = *(const float4*)&gm[q16*8];
    float4 g1v = *(const float4*)&gm[q16*8+4];
    float4 wa0 = *(const float4*)&waL[q16*8];
    float4 wa1 = *(const float4*)&waL[q16*8+4];
    float b_attn = *b_attn_p;
    const unsigned char* mrow = maskp + (long long)b*LW;

    auto sense_do = [&](uint4 e0, uint4 e1, uint4 e2, uint4 e3, uint4 e4, int w){
      float d0 = gsum16(dot8(e0, g0v, g1v));
      float d1 = gsum16(dot8(e1, g0v, g1v));
      float d2 = gsum16(dot8(e2, g0v, g1v));
      float d3 = gsum16(dot8(e3, g0v, g1v));
      float d4 = gsum16(dot8(e4, g0v, g1v));
      float mx = fmaxf(fmaxf(fmaxf(d0,d1), fmaxf(d2,d3)), d4);
      float x0 = __expf(d0-mx), x1 = __expf(d1-mx), x2 = __expf(d2-mx),
            x3 = __expf(d3-mx), x4 = __expf(d4-mx);
      float inv = 1.0f / (x0+x1+x2+x3+x4);
      float4 m0 = {0,0,0,0}, m1 = {0,0,0,0};
      wacc8(e0, x0*inv, m0, m1);
      wacc8(e1, x1*inv, m0, m1);
      wacc8(e2, x2*inv, m0, m1);
      wacc8(e3, x3*inv, m0, m1);
      wacc8(e4, x4*inv, m0, m1);
      *(float4*)&wm[w*DD + q16*8]     = m0;
      *(float4*)&wm[w*DD + q16*8 + 4] = m1;
      float wi = m0.x*wa0.x + m0.y*wa0.y + m0.z*wa0.z + m0.w*wa0.w
               + m1.x*wa1.x + m1.y*wa1.y + m1.z*wa1.z + m1.w*wa1.w;
      wi = gsum16(wi);
      if (q16 == 0) wimp[w] = mrow[w] ? -INFINITY : (wi + b_attn);
    };

    #pragma unroll
    for (int k = 0; k < 3; k++){
      int wA = G + k*64, wB = wA + 32;
      int ta = wA*NS, tb = wB*NS;
      uint4 a0 = *(const uint4*)(embB + (long long)idL[ta  ]*64 + (q16<<2));
      uint4 a1 = *(const uint4*)(embB + (long long)idL[ta+1]*64 + (q16<<2));
      uint4 a2 = *(const uint4*)(embB + (long long)idL[ta+2]*64 + (q16<<2));
      uint4 a3 = *(const uint4*)(embB + (long long)idL[ta+3]*64 + (q16<<2));
      uint4 a4 = *(const uint4*)(embB + (long long)idL[ta+4]*64 + (q16<<2));
      uint4 c0 = *(const uint4*)(embB + (long long)idL[tb  ]*64 + (q16<<2));
      uint4 c1 = *(const uint4*)(embB + (long long)idL[tb+1]*64 + (q16<<2));
      uint4 c2 = *(const uint4*)(embB + (long long)idL[tb+2]*64 + (q16<<2));
      uint4 c3 = *(const uint4*)(embB + (long long)idL[tb+3]*64 + (q16<<2));
      uint4 c4 = *(const uint4*)(embB + (long long)idL[tb+4]*64 + (q16<<2));
      sense_do(a0, a1, a2, a3, a4, wA);
      sense_do(c0, c1, c2, c3, c4, wB);
    }
    if (G < 8){
      int wA = 192 + G, ta = wA*NS;
      uint4 a0 = *(const uint4*)(embB + (long long)idL[ta  ]*64 + (q16<<2));
      uint4 a1 = *(const uint4*)(embB + (long long)idL[ta+1]*64 + (q16<<2));
      uint4 a2 = *(const uint4*)(embB + (long long)idL[ta+2]*64 + (q16<<2));
      uint4 a3 = *(const uint4*)(embB + (long long)idL[ta+3]*64 + (q16<<2));
      uint4 a4 = *(const uint4*)(embB + (long long)idL[ta+4]*64 + (q16<<2));
      sense_do(a0, a1, a2, a3, a4, wA);
    }
  }
  __syncthreads();

  // ---- word softmax over 200 (wave 0)
  if (wv == 0){
    float v[4]; float mx = -INFINITY;
    #pragma unroll
    for (int j = 0; j < 4; j++){
      int i = l + 64*j;
      v[j] = (i < LW) ? wimp[i] : -INFINITY;
      mx = fmaxf(mx, v[j]);
    }
    mx = wmax64(mx);
    float s = 0.f;
    #pragma unroll
    for (int j = 0; j < 4; j++){
      int i = l + 64*j;
      if (i < LW){ v[j] = __expf(v[j]-mx); s += v[j]; }
    }
    s = wsum64(s);
    float inv = 1.0f / s;
    #pragma unroll
    for (int j = 0; j < 4; j++){
      int i = l + 64*j;
      if (i < LW) ww[i] = v[j]*inv;
    }
  }
  __syncthreads();

  // ---- ctx = sum_w ww[w] * wm[w]  (pure LDS; 4 row-groups of 128 threads)
  {
    int d = t & 127, r = t >> 7;   // r in 0..3
    float s = 0.f;
    for (int w = r; w < LW; w += 4) s += ww[w]*wm[w*DD + d];
    red[r*DD + d] = s;
  }
  __syncthreads();
  if (t < DD){
    float s = red[t] + red[DD + t] + red[2*DD + t] + red[3*DD + t];
    cx[t] = s;
  }
  __syncthreads();

  // ---- Sweep 3: d2 -> sense softmax -> aw -> hidden; 2-word ILP
  {
    float4 c0v = *(const float4*)&cx[q16*8];
    float4 c1v = *(const float4*)&cx[q16*8+4];
    float4 h0a = {0,0,0,0}, h1a = {0,0,0,0};

    auto sim_do = [&](uint4 e0, uint4 e1, uint4 e2, uint4 e3, uint4 e4, int tb){
      int i0 = idL[tb], i1 = idL[tb+1], i2 = idL[tb+2],
          i3 = idL[tb+3], i4 = idL[tb+4];
      float d0 = gsum16(dot8(e0, c0v, c1v));
      float d1 = gsum16(dot8(e1, c0v, c1v));
      float d2 = gsum16(dot8(e2, c0v, c1v));
      float d3 = gsum16(dot8(e3, c0v, c1v));
      float d4 = gsum16(dot8(e4, c0v, c1v));
      float mx = fmaxf(fmaxf(fmaxf(d0,d1), fmaxf(d2,d3)), d4);
      float x0 = __expf(d0-mx), x1 = __expf(d1-mx), x2 = __expf(d2-mx),
            x3 = __expf(d3-mx), x4 = __expf(d4-mx);
      float inv = lw / (x0+x1+x2+x3+x4);
      wacc8(e0, (i0 == 0) ? 0.f : x0*inv, h0a, h1a);
      wacc8(e1, (i1 == 0) ? 0.f : x1*inv, h0a, h1a);
      wacc8(e2, (i2 == 0) ? 0.f : x2*inv, h0a, h1a);
      wacc8(e3, (i3 == 0) ? 0.f : x3*inv, h0a, h1a);
      wacc8(e4, (i4 == 0) ? 0.f : x4*inv, h0a, h1a);
    };

    #pragma unroll
    for (int k = 0; k < 3; k++){
      int wA = G + k*64, wB = wA + 32;
      int ta = wA*NS, tb = wB*NS;
      uint4 a0 = *(const uint4*)(embB + (long long)idL[ta  ]*64 + (q16<<2));
      uint4 a1 = *(const uint4*)(embB + (long long)idL[ta+1]*64 + (q16<<2));
      uint4 a2 = *(const uint4*)(embB + (long long)idL[ta+2]*64 + (q16<<2));
      uint4 a3 = *(const uint4*)(embB + (long long)idL[ta+3]*64 + (q16<<2));
      uint4 a4 = *(const uint4*)(embB + (long long)idL[ta+4]*64 + (q16<<2));
      uint4 c0 = *(const uint4*)(embB + (long long)idL[tb  ]*64 + (q16<<2));
      uint4 c1 = *(const uint4*)(embB + (long long)idL[tb+1]*64 + (q16<<2));
      uint4 c2 = *(const uint4*)(embB + (long long)idL[tb+2]*64 + (q16<<2));
      uint4 c3 = *(const uint4*)(embB + (long long)idL[tb+3]*64 + (q16<<2));
      uint4 c4 = *(const uint4*)(embB + (long long)idL[tb+4]*64 + (q16<<2));
      sim_do(a0, a1, a2, a3, a4, ta);
      sim_do(c0, c1, c2, c3, c4, tb);
    }
    if (G < 8){
      int wA = 192 + G, ta = wA*NS;
      uint4 a0 = *(const uint4*)(embB + (long long)idL[ta  ]*64 + (q16<<2));
      uint4 a1 = *(const uint4*)(embB + (long long)idL[ta+1]*64 + (q16<<2));
      uint4 a2 = *(const uint4*)(embB + (long long)idL[ta+2]*64 + (q16<<2));
      uint4 a3 = *(const uint4*)(embB + (long long)idL[ta+3]*64 + (q16<<2));
      uint4 a4 = *(const uint4*)(embB + (long long)idL[ta+4]*64 + (q16<<2));
      sim_do(a0, a1, a2, a3, a4, ta);
    }

    h0a.x = xg(h0a.x); h0a.y = xg(h0a.y); h0a.z = xg(h0a.z); h0a.w = xg(h0a.w);
    h1a.x = xg(h1a.x); h1a.y = xg(h1a.y); h1a.z = xg(h1a.z); h1a.w = xg(h1a.w);
    if (g == 0){
      *(float4*)&red[wv*DD + q16*8]     = h0a;
      *(float4*)&red[wv*DD + q16*8 + 4] = h1a;
    }
  }
  __syncthreads();
  if (t < DD){
    float s = 0.f;
    #pragma unroll
    for (int r = 0; r < 8; r++) s += red[r*DD + t];
    hB[b*DD + t] = f2bf(s);
  }
}

// ---------------------------------------------------------------------------
// GEMM pass 1 (r12 proven): per-stripe sumexp stats only. 16 KB LDS.
__global__ __launch_bounds__(256) void k_gemm_stats(
    const unsigned short* __restrict__ Wt,   // [50000][128] bf16
    const unsigned short* __restrict__ hB,   // [256][128] bf16
    const float* __restrict__ b_out,
    float* __restrict__ stats)               // [256][NSTRIPES]
{
  __shared__ unsigned short Bs[64*128];      // XOR-swizzled
  int blk = blockIdx.x;
  long long n0 = (long long)blk * 64;
  int t = threadIdx.x;

  #pragma unroll
  for (int c = t; c < 1024; c += 256){
    int n = c >> 4;
    int bo = (c & 15) << 4;
    long long ng = n0 + n;
    uint4 v = {0u,0u,0u,0u};
    if (ng < OO) v = *(const uint4*)((const char*)Wt + ng*256 + bo);
    *(uint4*)((char*)Bs + n*256 + (bo ^ ((n & 7) << 4))) = v;
  }
  __syncthreads();

  int wv = t >> 6, l = t & 63;
  int lr = l & 15, lg = l >> 4;

  bf16x8 a[4][4];
  #pragma unroll
  for (int mt = 0; mt < 4; mt++)
    #pragma unroll
    for (int ks = 0; ks < 4; ks++)
      a[mt][ks] = *(const bf16x8*)(hB + (wv*64 + mt*16 + lr)*DD + ks*32 + lg*8);

  f32x4 acc[4][4];
  #pragma unroll
  for (int mt = 0; mt < 4; mt++)
    #pragma unroll
    for (int nt = 0; nt < 4; nt++)
      acc[mt][nt] = (f32x4){0.f,0.f,0.f,0.f};

  #pragma unroll
  for (int nt = 0; nt < 4; nt++)
    #pragma unroll
    for (int ks = 0; ks < 4; ks++){
      int n = nt*16 + lr;
      int kb = (ks*32 + lg*8) * 2;
      bf16x8 bfr = *(const bf16x8*)((const char*)Bs + n*256 + (kb ^ ((n & 7) << 4)));
      #pragma unroll
      for (int mt = 0; mt < 4; mt++)
        acc[mt][nt] = __builtin_amdgcn_mfma_f32_16x16x32_bf16(a[mt][ks], bfr, acc[mt][nt], 0, 0, 0);
    }

  float bv[4]; int nvalid[4];
  #pragma unroll
  for (int nt = 0; nt < 4; nt++){
    long long ng = n0 + nt*16 + lr;
    nvalid[nt] = (ng < OO);
    bv[nt] = nvalid[nt] ? b_out[ng] : 0.f;
  }
  #pragma unroll
  for (int mt = 0; mt < 4; mt++){
    #pragma unroll
    for (int j = 0; j < 4; j++){
      int m = wv*64 + mt*16 + lg*4 + j;   // C/D: col=lane&15, row=(lane>>4)*4+reg
      float s = 0.f;
      #pragma unroll
      for (int nt = 0; nt < 4; nt++)
        s += nvalid[nt] ? __expf(acc[mt][nt][j] + bv[nt]) : 0.f;
      #pragma unroll
      for (int o = 1; o < 16; o <<= 1) s += __shfl_xor(s, o, 64);
      if (lr == 0) stats[(long long)m*NSTRIPES + blk] = s;
    }
  }
}

// ---------------------------------------------------------------------------
// Row reduce (r22 proven): 256 threads per row, coalesced, LDS-combine.
__global__ __launch_bounds__(256) void k_reduce(
    const float* __restrict__ stats, float* __restrict__ Lrow){
  __shared__ float part[4];
  int m = blockIdx.x, t = threadIdx.x;
  float s = 0.f;
  for (int i = t; i < NSTRIPES; i += 256) s += stats[(long long)m*NSTRIPES + i];
  s = wsum64(s);
  if ((t & 63) == 0) part[t >> 6] = s;
  __syncthreads();
  if (t == 0) Lrow[m] = __logf(part[0] + part[1] + part[2] + part[3]);
}

// ---------------------------------------------------------------------------
// GEMM pass 2 (r20 proven): recompute logits, out = x - L, coalesced f32
// stores via a two-phase 128x65 f32 LDS transpose (49 KB -> 3 blocks/CU).
__global__ __launch_bounds__(256) void k_gemm_out(
    const unsigned short* __restrict__ Wt,
    const unsigned short* __restrict__ hB,
    const float* __restrict__ b_out,
    const float* __restrict__ Lrow,
    float* __restrict__ out)                 // [256][50000] f32
{
  __shared__ unsigned short Bs[64*128];      // 16 KB
  __shared__ float T2[128*65];               // 33 KB
  int blk = blockIdx.x;
  long long n0 = (long long)blk * 64;
  int t = threadIdx.x;

  #pragma unroll
  for (int c = t; c < 1024; c += 256){
    int n = c >> 4;
    int bo = (c & 15) << 4;
    long long ng = n0 + n;
    uint4 v = {0u,0u,0u,0u};
    if (ng < OO) v = *(const uint4*)((const char*)Wt + ng*256 + bo);
    *(uint4*)((char*)Bs + n*256 + (bo ^ ((n & 7) << 4))) = v;
  }
  __syncthreads();

  int wv = t >> 6, l = t & 63;
  int lr = l & 15, lg = l >> 4;

  bf16x8 a[4][4];
  #pragma unroll
  for (int mt = 0; mt < 4; mt++)
    #pragma unroll
    for (int ks = 0; ks < 4; ks++)
      a[mt][ks] = *(const bf16x8*)(hB + (wv*64 + mt*16 + lr)*DD + ks*32 + lg*8);

  f32x4 acc[4][4];
  #pragma unroll
  for (int mt = 0; mt < 4; mt++)
    #pragma unroll
    for (int nt = 0; nt < 4; nt++)
      acc[mt][nt] = (f32x4){0.f,0.f,0.f,0.f};

  #pragma unroll
  for (int nt = 0; nt < 4; nt++)
    #pragma unroll
    for (int ks = 0; ks < 4; ks++){
      int n = nt*16 + lr;
      int kb = (ks*32 + lg*8) * 2;
      bf16x8 bfr = *(const bf16x8*)((const char*)Bs + n*256 + (kb ^ ((n & 7) << 4)));
      #pragma unroll
      for (int mt = 0; mt < 4; mt++)
        acc[mt][nt] = __builtin_amdgcn_mfma_f32_16x16x32_bf16(a[mt][ks], bfr, acc[mt][nt], 0, 0, 0);
    }

  float bv[4];
  #pragma unroll
  for (int nt = 0; nt < 4; nt++){
    long long ng = n0 + nt*16 + lr;
    bv[nt] = (ng < OO) ? b_out[ng] : 0.f;
  }

  int vc = (int)((n0 + 64 <= OO) ? 64 : (OO - n0));   // valid cols this stripe

  #pragma unroll
  for (int half = 0; half < 2; half++){
    if ((wv >> 1) == half){
      #pragma unroll
      for (int mt = 0; mt < 4; mt++){
        #pragma unroll
        for (int j = 0; j < 4; j++){
          int m = wv*64 + mt*16 + lg*4 + j;
          int mr = m & 127;
          float Lv = Lrow[m];
          #pragma unroll
          for (int nt = 0; nt < 4; nt++)
            T2[mr*65 + nt*16 + lr] = acc[mt][nt][j] + bv[nt] - Lv;
        }
      }
    }
    __syncthreads();
    // store 128 rows x 64 cols: each wave streams 32 rows, 256B/row.
    for (int it = 0; it < 32; it++){
      int mr = wv*32 + it;
      long long m = half*128 + mr;
      if (l < vc) out[m*OO + n0 + l] = T2[mr*65 + l];
    }
    __syncthreads();
  }
}

// ---------------------------------------------------------------------------
extern "C" void kernel_launch(void* const* d_in, const int* in_sizes, int n_in,
                              void* d_out, int out_size, void* d_ws, size_t ws_size,
                              hipStream_t stream)
{
  (void)in_sizes; (void)n_in; (void)out_size; (void)ws_size;
  const void* inputs          = d_in[0];
  const float* lw             = (const float*)d_in[1];
  const unsigned char* mask   = (const unsigned char*)d_in[2];
  const float* emb            = (const float*)d_in[3];
  const float* W              = (const float*)d_in[4];
  const float* bout           = (const float*)d_in[5];
  const float* w_attn         = (const float*)d_in[6];
  const float* b_attn         = (const float*)d_in[7];

  char* ws = (char*)d_ws;
  unsigned short* Wt   = (unsigned short*)(ws);                // 12,800,000 B
  unsigned* embB       = (unsigned*)(ws + 12800000);           // 12,800,000 B
  unsigned short* hB   = (unsigned short*)(ws + 25600000);     //     65,536 B
  float* stats         = (float*)(ws + 25665536);              //    800,768 B
  float* Lrow          = (float*)(ws + 26466304);              //      1,024 B

  const int* in32 = (const int*)inputs;

  k_prep<<<NSTRIPES + EMB_BLK, 256, 0, stream>>>(W, emb, Wt, embB);
  k_attn<<<MB, 512, 0, stream>>>(in32, lw, mask, embB, w_attn, b_attn, hB);
  k_gemm_stats<<<NSTRIPES, 256, 0, stream>>>(Wt, hB, bout, stats);
  k_reduce<<<MB, 256, 0, stream>>>(stats, Lrow);
  k_gemm_out<<<NSTRIPES, 256, 0, stream>>>(Wt, hB, bout, Lrow, (float*)d_out);
}

// Round 24
// 89.236 us; speedup vs baseline: 1.0776x; 1.0776x over previous
//
#include <hip/hip_runtime.h>
#include <hip/hip_bf16.h>
#include <stdint.h>

// Problem constants (from reference setup_inputs)
#define MB 256
#define LW 200      // words per batch
#define NS 5        // senses per word
#define DD 128      // embedding dim
#define OO 50000    // output vocab
#define LSTOK 1000  // LW*NS

#define NSTRIPES 782   // ceil(50000/64)
#define EMB_BLK 391    // ceil(50000*128 / 16384)

typedef __attribute__((ext_vector_type(8))) short bf16x8;
typedef __attribute__((ext_vector_type(4))) float f32x4;

__device__ inline unsigned short f2bf(float f){
  unsigned u = __float_as_uint(f);
  unsigned r = (u + 0x7fffu + ((u >> 16) & 1u)) >> 16;  // RNE
  return (unsigned short)r;
}
__device__ inline unsigned packbf(float a, float b){
  return (unsigned)f2bf(a) | ((unsigned)f2bf(b) << 16);
}
__device__ inline float lo16f(unsigned p){ return __uint_as_float(p << 16); }
__device__ inline float hi16f(unsigned p){ return __uint_as_float(p & 0xffff0000u); }
__device__ inline float wsum64(float v){
  #pragma unroll
  for (int o = 1; o < 64; o <<= 1) v += __shfl_xor(v, o, 64);
  return v;
}
__device__ inline float wmax64(float v){
  #pragma unroll
  for (int o = 1; o < 64; o <<= 1) v = fmaxf(v, __shfl_xor(v, o, 64));
  return v;
}
// dot of 8 bf16 (packed in uint4) with 8 f32 (two float4)
__device__ inline float dot8(uint4 r, float4 a, float4 b){
  return lo16f(r.x)*a.x + hi16f(r.x)*a.y + lo16f(r.y)*a.z + hi16f(r.y)*a.w
       + lo16f(r.z)*b.x + hi16f(r.z)*b.y + lo16f(r.w)*b.z + hi16f(r.w)*b.w;
}
// unweighted accumulate of 8 bf16 into two float4
__device__ inline void acc8(uint4 r, float4& x, float4& y){
  x.x += lo16f(r.x); x.y += hi16f(r.x); x.z += lo16f(r.y); x.w += hi16f(r.y);
  y.x += lo16f(r.z); y.y += hi16f(r.z); y.z += lo16f(r.w); y.w += hi16f(r.w);
}
// weighted accumulate
__device__ inline void wacc8(uint4 r, float w, float4& x, float4& y){
  x.x += w*lo16f(r.x); x.y += w*hi16f(r.x); x.z += w*lo16f(r.y); x.w += w*hi16f(r.y);
  y.x += w*lo16f(r.z); y.y += w*hi16f(r.z); y.z += w*lo16f(r.w); y.w += w*hi16f(r.w);
}
// butterfly sum within 16-lane groups
__device__ inline float gsum16(float v){
  v += __shfl_xor(v, 1, 64);
  v += __shfl_xor(v, 2, 64);
  v += __shfl_xor(v, 4, 64);
  v += __shfl_xor(v, 8, 64);
  return v;
}
// cross-group (within-wave) sum
__device__ inline float xg(float v){
  v += __shfl_xor(v, 16, 64);
  v += __shfl_xor(v, 32, 64);
  return v;
}
// Per-wave int64-vs-int32 sniff: high dwords of first 64 elements all zero -> int64.
__device__ inline int sniff_f(const unsigned* p, int l){
  unsigned v = p[2*l + 1];
  return (__ballot(v != 0u) == 0ull) ? 1 : 0;
}

// ---------------------------------------------------------------------------
// k_prep (proven): blocks [0,NSTRIPES): W -> Wt (bf16, transposed)
//                  blocks [NSTRIPES, +EMB_BLK): emb f32 -> embB bf16
__global__ __launch_bounds__(256) void k_prep(const float* __restrict__ W,
                                              const float* __restrict__ emb,
                                              unsigned short* __restrict__ Wt,
                                              unsigned* __restrict__ embB){
  int blk = blockIdx.x, t = threadIdx.x;
  if (blk < NSTRIPES){
    __shared__ float tile[64][129];
    long long n0 = (long long)blk * 64;
    int j = t & 63, kk = t >> 6;
    #pragma unroll
    for (int k = kk; k < 128; k += 4){
      float v = 0.f;
      if (n0 + j < OO) v = W[(long long)k*OO + n0 + j];
      tile[j][k] = v;
    }
    __syncthreads();
    #pragma unroll
    for (int c = t; c < 4096; c += 256){
      int row = c >> 6, dw = c & 63;
      if (n0 + row < OO){
        unsigned pr = packbf(tile[row][2*dw], tile[row][2*dw+1]);
        ((unsigned*)Wt)[(n0 + row)*64 + dw] = pr;
      }
    }
  } else {
    long long base = (long long)(blk - NSTRIPES) * 16384;
    for (int i = t; i < 4096; i += 256){
      long long idx = base + (long long)i*4;
      if (idx < (long long)OO*DD){
        float4 v = *(const float4*)(emb + idx);
        uint2 o; o.x = packbf(v.x, v.y); o.y = packbf(v.z, v.w);
        *(uint2*)(embB + (idx >> 1)) = o;
      }
    }
  }
}

// ---------------------------------------------------------------------------
// Fused attention v7 (r12 proven, byte-identical).
__global__ __launch_bounds__(1024)
void k_attn(
    const int* __restrict__ in32, const float* __restrict__ lwp,
    const unsigned char* __restrict__ maskp, const unsigned* __restrict__ embB,
    const float* __restrict__ w_attn, const float* __restrict__ b_attn_p,
    unsigned short* __restrict__ hB)
{
  __shared__ float wm[LW*DD];    // word_mean f32: 100 KB
  __shared__ float red[16*DD];   // 8 KB
  __shared__ int   idL[1024];
  __shared__ float gm[DD];
  __shared__ float cx[DD];
  __shared__ float waL[DD];
  __shared__ float wimp[LW];
  __shared__ float ww[LW];

  int b = blockIdx.x, t = threadIdx.x;
  int wv = t >> 6, l = t & 63;
  int g = l >> 4, q16 = l & 15;
  int G = wv*4 + g;              // group id 0..63
  int f = sniff_f((const unsigned*)in32, l);
  long long base = (long long)b * LSTOK;
  float lw = lwp[b];

  idL[t] = (t < LSTOK) ? in32[(base + t) << f] : 0;
  if (t < DD) waL[t] = w_attn[t];
  __syncthreads();

  // ---- Sweep 1: gmean
  {
    float4 s0v = {0,0,0,0}, s1v = {0,0,0,0};
    #pragma unroll 4
    for (int j = 0; j < 16; j++){
      int id = idL[G*16 + j];
      uint4 r = *(const uint4*)(embB + (long long)id*64 + (q16 << 2));
      acc8(r, s0v, s1v);
    }
    s0v.x = xg(s0v.x); s0v.y = xg(s0v.y); s0v.z = xg(s0v.z); s0v.w = xg(s0v.w);
    s1v.x = xg(s1v.x); s1v.y = xg(s1v.y); s1v.z = xg(s1v.z); s1v.w = xg(s1v.w);
    if (g == 0){
      *(float4*)&red[wv*DD + q16*8]     = s0v;
      *(float4*)&red[wv*DD + q16*8 + 4] = s1v;
    }
  }
  __syncthreads();
  if (t < DD){
    float s = 0.f;
    #pragma unroll
    for (int r = 0; r < 16; r++) s += red[r*DD + t];
    gm[t] = s * lw * 0.2f;
  }
  __syncthreads();

  // ---- Sweep 2: d1 -> sense softmax -> word_mean + wimp
  {
    float4 g0v = *(const float4*)&gm[q16*8];
    float4 g1v = *(const float4*)&gm[q16*8+4];
    float4 wa0 = *(const float4*)&waL[q16*8];
    float4 wa1 = *(const float4*)&waL[q16*8+4];
    float b_attn = *b_attn_p;
    for (int w = G; w < LW; w += 64){
      int tb = w*NS;
      uint4 e0 = *(const uint4*)(embB + (long long)idL[tb  ]*64 + (q16<<2));
      uint4 e1 = *(const uint4*)(embB + (long long)idL[tb+1]*64 + (q16<<2));
      uint4 e2 = *(const uint4*)(embB + (long long)idL[tb+2]*64 + (q16<<2));
      uint4 e3 = *(const uint4*)(embB + (long long)idL[tb+3]*64 + (q16<<2));
      uint4 e4 = *(const uint4*)(embB + (long long)idL[tb+4]*64 + (q16<<2));
      float d0 = gsum16(dot8(e0, g0v, g1v));
      float d1 = gsum16(dot8(e1, g0v, g1v));
      float d2 = gsum16(dot8(e2, g0v, g1v));
      float d3 = gsum16(dot8(e3, g0v, g1v));
      float d4 = gsum16(dot8(e4, g0v, g1v));
      float mx = fmaxf(fmaxf(fmaxf(d0,d1), fmaxf(d2,d3)), d4);
      float x0 = __expf(d0-mx), x1 = __expf(d1-mx), x2 = __expf(d2-mx),
            x3 = __expf(d3-mx), x4 = __expf(d4-mx);
      float inv = 1.0f / (x0+x1+x2+x3+x4);
      float4 m0 = {0,0,0,0}, m1 = {0,0,0,0};
      wacc8(e0, x0*inv, m0, m1);
      wacc8(e1, x1*inv, m0, m1);
      wacc8(e2, x2*inv, m0, m1);
      wacc8(e3, x3*inv, m0, m1);
      wacc8(e4, x4*inv, m0, m1);
      *(float4*)&wm[w*DD + q16*8]     = m0;
      *(float4*)&wm[w*DD + q16*8 + 4] = m1;
      float wi = m0.x*wa0.x + m0.y*wa0.y + m0.z*wa0.z + m0.w*wa0.w
               + m1.x*wa1.x + m1.y*wa1.y + m1.z*wa1.z + m1.w*wa1.w;
      wi = gsum16(wi);
      if (q16 == 0)
        wimp[w] = maskp[(long long)b*LW + w] ? -INFINITY : (wi + b_attn);
    }
  }
  __syncthreads();

  // ---- word softmax over 200 (wave 0)
  if (wv == 0){
    float v[4]; float mx = -INFINITY;
    #pragma unroll
    for (int j = 0; j < 4; j++){
      int i = l + 64*j;
      v[j] = (i < LW) ? wimp[i] : -INFINITY;
      mx = fmaxf(mx, v[j]);
    }
    mx = wmax64(mx);
    float s = 0.f;
    #pragma unroll
    for (int j = 0; j < 4; j++){
      int i = l + 64*j;
      if (i < LW){ v[j] = __expf(v[j]-mx); s += v[j]; }
    }
    s = wsum64(s);
    float inv = 1.0f / s;
    #pragma unroll
    for (int j = 0; j < 4; j++){
      int i = l + 64*j;
      if (i < LW) ww[i] = v[j]*inv;
    }
  }
  __syncthreads();

  // ---- ctx = sum_w ww[w] * wm[w]  (pure LDS)
  {
    int d = t & 127, r = t >> 7;
    float s = 0.f;
    for (int w = r; w < LW; w += 8) s += ww[w]*wm[w*DD + d];
    red[r*DD + d] = s;
  }
  __syncthreads();
  if (t < DD){
    float s = 0.f;
    #pragma unroll
    for (int r = 0; r < 8; r++) s += red[r*DD + t];
    cx[t] = s;
  }
  __syncthreads();

  // ---- Sweep 3: d2 -> sense softmax -> aw -> hidden
  {
    float4 c0v = *(const float4*)&cx[q16*8];
    float4 c1v = *(const float4*)&cx[q16*8+4];
    float4 h0a = {0,0,0,0}, h1a = {0,0,0,0};
    for (int w = G; w < LW; w += 64){
      int tb = w*NS;
      int i0 = idL[tb], i1 = idL[tb+1], i2 = idL[tb+2], i3 = idL[tb+3], i4 = idL[tb+4];
      uint4 e0 = *(const uint4*)(embB + (long long)i0*64 + (q16<<2));
      uint4 e1 = *(const uint4*)(embB + (long long)i1*64 + (q16<<2));
      uint4 e2 = *(const uint4*)(embB + (long long)i2*64 + (q16<<2));
      uint4 e3 = *(const uint4*)(embB + (long long)i3*64 + (q16<<2));
      uint4 e4 = *(const uint4*)(embB + (long long)i4*64 + (q16<<2));
      float d0 = gsum16(dot8(e0, c0v, c1v));
      float d1 = gsum16(dot8(e1, c0v, c1v));
      float d2 = gsum16(dot8(e2, c0v, c1v));
      float d3 = gsum16(dot8(e3, c0v, c1v));
      float d4 = gsum16(dot8(e4, c0v, c1v));
      float mx = fmaxf(fmaxf(fmaxf(d0,d1), fmaxf(d2,d3)), d4);
      float x0 = __expf(d0-mx), x1 = __expf(d1-mx), x2 = __expf(d2-mx),
            x3 = __expf(d3-mx), x4 = __expf(d4-mx);
      float inv = lw / (x0+x1+x2+x3+x4);
      wacc8(e0, (i0 == 0) ? 0.f : x0*inv, h0a, h1a);
      wacc8(e1, (i1 == 0) ? 0.f : x1*inv, h0a, h1a);
      wacc8(e2, (i2 == 0) ? 0.f : x2*inv, h0a, h1a);
      wacc8(e3, (i3 == 0) ? 0.f : x3*inv, h0a, h1a);
      wacc8(e4, (i4 == 0) ? 0.f : x4*inv, h0a, h1a);
    }
    h0a.x = xg(h0a.x); h0a.y = xg(h0a.y); h0a.z = xg(h0a.z); h0a.w = xg(h0a.w);
    h1a.x = xg(h1a.x); h1a.y = xg(h1a.y); h1a.z = xg(h1a.z); h1a.w = xg(h1a.w);
    if (g == 0){
      *(float4*)&red[wv*DD + q16*8]     = h0a;
      *(float4*)&red[wv*DD + q16*8 + 4] = h1a;
    }
  }
  __syncthreads();
  if (t < DD){
    float s = 0.f;
    #pragma unroll
    for (int r = 0; r < 16; r++) s += red[r*DD + t];
    hB[b*DD + t] = f2bf(s);
  }
}

// ---------------------------------------------------------------------------
// GEMM pass 1 (r12 proven): per-stripe sumexp stats only. 16 KB LDS.
__global__ __launch_bounds__(256) void k_gemm_stats(
    const unsigned short* __restrict__ Wt,   // [50000][128] bf16
    const unsigned short* __restrict__ hB,   // [256][128] bf16
    const float* __restrict__ b_out,
    float* __restrict__ stats)               // [256][NSTRIPES]
{
  __shared__ unsigned short Bs[64*128];      // XOR-swizzled
  int blk = blockIdx.x;
  long long n0 = (long long)blk * 64;
  int t = threadIdx.x;

  #pragma unroll
  for (int c = t; c < 1024; c += 256){
    int n = c >> 4;
    int bo = (c & 15) << 4;
    long long ng = n0 + n;
    uint4 v = {0u,0u,0u,0u};
    if (ng < OO) v = *(const uint4*)((const char*)Wt + ng*256 + bo);
    *(uint4*)((char*)Bs + n*256 + (bo ^ ((n & 7) << 4))) = v;
  }
  __syncthreads();

  int wv = t >> 6, l = t & 63;
  int lr = l & 15, lg = l >> 4;

  bf16x8 a[4][4];
  #pragma unroll
  for (int mt = 0; mt < 4; mt++)
    #pragma unroll
    for (int ks = 0; ks < 4; ks++)
      a[mt][ks] = *(const bf16x8*)(hB + (wv*64 + mt*16 + lr)*DD + ks*32 + lg*8);

  f32x4 acc[4][4];
  #pragma unroll
  for (int mt = 0; mt < 4; mt++)
    #pragma unroll
    for (int nt = 0; nt < 4; nt++)
      acc[mt][nt] = (f32x4){0.f,0.f,0.f,0.f};

  #pragma unroll
  for (int nt = 0; nt < 4; nt++)
    #pragma unroll
    for (int ks = 0; ks < 4; ks++){
      int n = nt*16 + lr;
      int kb = (ks*32 + lg*8) * 2;
      bf16x8 bfr = *(const bf16x8*)((const char*)Bs + n*256 + (kb ^ ((n & 7) << 4)));
      #pragma unroll
      for (int mt = 0; mt < 4; mt++)
        acc[mt][nt] = __builtin_amdgcn_mfma_f32_16x16x32_bf16(a[mt][ks], bfr, acc[mt][nt], 0, 0, 0);
    }

  float bv[4]; int nvalid[4];
  #pragma unroll
  for (int nt = 0; nt < 4; nt++){
    long long ng = n0 + nt*16 + lr;
    nvalid[nt] = (ng < OO);
    bv[nt] = nvalid[nt] ? b_out[ng] : 0.f;
  }
  #pragma unroll
  for (int mt = 0; mt < 4; mt++){
    #pragma unroll
    for (int j = 0; j < 4; j++){
      int m = wv*64 + mt*16 + lg*4 + j;   // C/D: col=lane&15, row=(lane>>4)*4+reg
      float s = 0.f;
      #pragma unroll
      for (int nt = 0; nt < 4; nt++)
        s += nvalid[nt] ? __expf(acc[mt][nt][j] + bv[nt]) : 0.f;
      #pragma unroll
      for (int o = 1; o < 16; o <<= 1) s += __shfl_xor(s, o, 64);
      if (lr == 0) stats[(long long)m*NSTRIPES + blk] = s;
    }
  }
}

// ---------------------------------------------------------------------------
// Row reduce (r22 proven): 256 threads per row, coalesced, LDS-combine.
__global__ __launch_bounds__(256) void k_reduce(
    const float* __restrict__ stats, float* __restrict__ Lrow){
  __shared__ float part[4];
  int m = blockIdx.x, t = threadIdx.x;
  float s = 0.f;
  for (int i = t; i < NSTRIPES; i += 256) s += stats[(long long)m*NSTRIPES + i];
  s = wsum64(s);
  if ((t & 63) == 0) part[t >> 6] = s;
  __syncthreads();
  if (t == 0) Lrow[m] = __logf(part[0] + part[1] + part[2] + part[3]);
}

// ---------------------------------------------------------------------------
// GEMM pass 2 (r20 proven): recompute logits, out = x - L, coalesced f32
// stores via a two-phase 128x65 f32 LDS transpose (49 KB -> 3 blocks/CU).
__global__ __launch_bounds__(256) void k_gemm_out(
    const unsigned short* __restrict__ Wt,
    const unsigned short* __restrict__ hB,
    const float* __restrict__ b_out,
    const float* __restrict__ Lrow,
    float* __restrict__ out)                 // [256][50000] f32
{
  __shared__ unsigned short Bs[64*128];      // 16 KB
  __shared__ float T2[128*65];               // 33 KB
  int blk = blockIdx.x;
  long long n0 = (long long)blk * 64;
  int t = threadIdx.x;

  #pragma unroll
  for (int c = t; c < 1024; c += 256){
    int n = c >> 4;
    int bo = (c & 15) << 4;
    long long ng = n0 + n;
    uint4 v = {0u,0u,0u,0u};
    if (ng < OO) v = *(const uint4*)((const char*)Wt + ng*256 + bo);
    *(uint4*)((char*)Bs + n*256 + (bo ^ ((n & 7) << 4))) = v;
  }
  __syncthreads();

  int wv = t >> 6, l = t & 63;
  int lr = l & 15, lg = l >> 4;

  bf16x8 a[4][4];
  #pragma unroll
  for (int mt = 0; mt < 4; mt++)
    #pragma unroll
    for (int ks = 0; ks < 4; ks++)
      a[mt][ks] = *(const bf16x8*)(hB + (wv*64 + mt*16 + lr)*DD + ks*32 + lg*8);

  f32x4 acc[4][4];
  #pragma unroll
  for (int mt = 0; mt < 4; mt++)
    #pragma unroll
    for (int nt = 0; nt < 4; nt++)
      acc[mt][nt] = (f32x4){0.f,0.f,0.f,0.f};

  #pragma unroll
  for (int nt = 0; nt < 4; nt++)
    #pragma unroll
    for (int ks = 0; ks < 4; ks++){
      int n = nt*16 + lr;
      int kb = (ks*32 + lg*8) * 2;
      bf16x8 bfr = *(const bf16x8*)((const char*)Bs + n*256 + (kb ^ ((n & 7) << 4)));
      #pragma unroll
      for (int mt = 0; mt < 4; mt++)
        acc[mt][nt] = __builtin_amdgcn_mfma_f32_16x16x32_bf16(a[mt][ks], bfr, acc[mt][nt], 0, 0, 0);
    }

  float bv[4];
  #pragma unroll
  for (int nt = 0; nt < 4; nt++){
    long long ng = n0 + nt*16 + lr;
    bv[nt] = (ng < OO) ? b_out[ng] : 0.f;
  }

  int vc = (int)((n0 + 64 <= OO) ? 64 : (OO - n0));   // valid cols this stripe

  #pragma unroll
  for (int half = 0; half < 2; half++){
    if ((wv >> 1) == half){
      #pragma unroll
      for (int mt = 0; mt < 4; mt++){
        #pragma unroll
        for (int j = 0; j < 4; j++){
          int m = wv*64 + mt*16 + lg*4 + j;
          int mr = m & 127;
          float Lv = Lrow[m];
          #pragma unroll
          for (int nt = 0; nt < 4; nt++)
            T2[mr*65 + nt*16 + lr] = acc[mt][nt][j] + bv[nt] - Lv;
        }
      }
    }
    __syncthreads();
    // store 128 rows x 64 cols: each wave streams 32 rows, 256B/row.
    for (int it = 0; it < 32; it++){
      int mr = wv*32 + it;
      long long m = half*128 + mr;
      if (l < vc) out[m*OO + n0 + l] = T2[mr*65 + l];
    }
    __syncthreads();
  }
}

// ---------------------------------------------------------------------------
extern "C" void kernel_launch(void* const* d_in, const int* in_sizes, int n_in,
                              void* d_out, int out_size, void* d_ws, size_t ws_size,
                              hipStream_t stream)
{
  (void)in_sizes; (void)n_in; (void)out_size; (void)ws_size;
  const void* inputs          = d_in[0];
  const float* lw             = (const float*)d_in[1];
  const unsigned char* mask   = (const unsigned char*)d_in[2];
  const float* emb            = (const float*)d_in[3];
  const float* W              = (const float*)d_in[4];
  const float* bout           = (const float*)d_in[5];
  const float* w_attn         = (const float*)d_in[6];
  const float* b_attn         = (const float*)d_in[7];

  char* ws = (char*)d_ws;
  unsigned short* Wt   = (unsigned short*)(ws);                // 12,800,000 B
  unsigned* embB       = (unsigned*)(ws + 12800000);           // 12,800,000 B
  unsigned short* hB   = (unsigned short*)(ws + 25600000);     //     65,536 B
  float* stats         = (float*)(ws + 25665536);              //    800,768 B
  float* Lrow          = (float*)(ws + 26466304);              //      1,024 B

  const int* in32 = (const int*)inputs;

  k_prep<<<NSTRIPES + EMB_BLK, 256, 0, stream>>>(W, emb, Wt, embB);
  k_attn<<<MB, 1024, 0, stream>>>(in32, lw, mask, embB, w_attn, b_attn, hB);
  k_gemm_stats<<<NSTRIPES, 256, 0, stream>>>(Wt, hB, bout, stats);
  k_reduce<<<MB, 256, 0, stream>>>(stats, Lrow);
  k_gemm_out<<<NSTRIPES, 256, 0, stream>>>(Wt, hB, bout, Lrow, (float*)d_out);
}